// Round 1
// baseline (555.533 us; speedup 1.0000x reference)
//
#include <hip/hip_runtime.h>
#include <hip/hip_bf16.h>
#include <stdint.h>

typedef __attribute__((ext_vector_type(8))) short short8;
typedef __attribute__((ext_vector_type(4))) float floatx4;

// Q pre-scale: 0.125 (1/sqrt(K)) * log2(e), so exp(s/8) == exp2(q'.k)
#define QSCALE 0.18033688f

__device__ __forceinline__ unsigned short f2bf(float f) {
    unsigned int u = __float_as_uint(f);
    u += 0x7fffu + ((u >> 16) & 1u);
    return (unsigned short)(u >> 16);
}
__device__ __forceinline__ unsigned int pack2bf(float a, float b) {
    __hip_bfloat162 h = __float22bfloat162_rn(make_float2(a, b));
    return *reinterpret_cast<unsigned int*>(&h);
}

// async global->LDS, 16B per lane; LDS dst must be wave-uniform base + lane*16
__device__ __forceinline__ void async16(const void* g, void* l) {
    __builtin_amdgcn_global_load_lds(
        (const __attribute__((address_space(1))) unsigned int*)g,
        (__attribute__((address_space(3))) unsigned int*)l, 16, 0, 0);
}

// ---------------------------------------------------------------------------
// cvt: fp32 -> bf16, 8 elements/thread
// ---------------------------------------------------------------------------
__global__ __launch_bounds__(256) void cvt_bf16(const float* __restrict__ src,
                                                unsigned short* __restrict__ dst, int n8) {
    int i = blockIdx.x * 256 + threadIdx.x;
    if (i >= n8) return;
    const float4 a = ((const float4*)src)[2 * i];
    const float4 b = ((const float4*)src)[2 * i + 1];
    ushort4 lo, hi;
    lo.x = f2bf(a.x); lo.y = f2bf(a.y); lo.z = f2bf(a.z); lo.w = f2bf(a.w);
    hi.x = f2bf(b.x); hi.y = f2bf(b.y); hi.z = f2bf(b.z); hi.w = f2bf(b.w);
    ((ushort4*)dst)[2 * i] = lo;
    ((ushort4*)dst)[2 * i + 1] = hi;
}

// ---------------------------------------------------------------------------
// tcvt: fp32 [R][C] -> bf16 [C][R]  (64x64 tiles via LDS)
// ---------------------------------------------------------------------------
__global__ __launch_bounds__(256) void tcvt(const float* __restrict__ src,
                                            unsigned short* __restrict__ dst, int R, int C) {
    __shared__ unsigned short t[64][72];
    const int tid = threadIdx.x;
    const int r0 = blockIdx.y * 64, c0 = blockIdx.x * 64;
    #pragma unroll
    for (int it = 0; it < 4; it++) {
        int idx = it * 256 + tid;
        int rr = idx >> 4, cc = (idx & 15) * 4;
        float4 v = *(const float4*)(src + (size_t)(r0 + rr) * C + c0 + cc);
        t[cc + 0][rr] = f2bf(v.x);
        t[cc + 1][rr] = f2bf(v.y);
        t[cc + 2][rr] = f2bf(v.z);
        t[cc + 3][rr] = f2bf(v.w);
    }
    __syncthreads();
    #pragma unroll
    for (int it = 0; it < 2; it++) {
        int idx = it * 256 + tid;
        int cc = idx >> 3, r8 = (idx & 7) * 8;
        short8 v = *(const short8*)&t[cc][r8];
        *(short8*)(dst + (size_t)(c0 + cc) * R + r0 + r8) = v;
    }
}

// ---------------------------------------------------------------------------
// vtrans: vb[bh][2048][64] -> vbt[bh][64][2048]  (64x64 tiles via LDS)
// ---------------------------------------------------------------------------
__global__ __launch_bounds__(256) void vtrans(const unsigned short* __restrict__ vb,
                                              unsigned short* __restrict__ vbt) {
    __shared__ unsigned short t[64][72];
    const int tid = threadIdx.x;
    const int bh = blockIdx.y, m0 = blockIdx.x * 64;
    const unsigned short* src = vb + ((size_t)bh * 2048 + m0) * 64;
    unsigned short* dst = vbt + ((size_t)bh << 17) + m0;
    union { short8 v; unsigned short u[8]; } tmp;
    #pragma unroll
    for (int it = 0; it < 2; it++) {
        int idx = it * 256 + tid;
        int m = idx >> 3, c8 = (idx & 7) * 8;
        tmp.v = *(const short8*)(src + (size_t)m * 64 + c8);
        #pragma unroll
        for (int j = 0; j < 8; j++) t[c8 + j][m] = tmp.u[j];
    }
    __syncthreads();
    #pragma unroll
    for (int it = 0; it < 2; it++) {
        int idx = it * 256 + tid;
        int k = idx >> 3, c8 = (idx & 7) * 8;
        short8 v = *(const short8*)&t[k][c8];
        *(short8*)(dst + (size_t)k * 2048 + c8) = v;
    }
}

// ---------------------------------------------------------------------------
// qkv_gemm (128x128 tile, BK=32) with async global->LDS staging (16B/lane).
// ---------------------------------------------------------------------------
__global__ __launch_bounds__(256) void qkv_gemm(
    const unsigned short* __restrict__ A, const unsigned short* __restrict__ Bt,
    unsigned short* __restrict__ qb, unsigned short* __restrict__ kb,
    unsigned short* __restrict__ vb)
{
    __shared__ __align__(16) unsigned short As[128 * 32];
    __shared__ __align__(16) unsigned short Bs[128 * 32];
    const int tid = threadIdx.x, wave = tid >> 6, lane = tid & 63;
    const int quad = lane >> 4, lr = lane & 15;
    const int wr = wave >> 1, wc = wave & 1;
    const int bm = blockIdx.y * 128, bn = blockIdx.x * 128;
    const int lrow = lane >> 2, lcol = (lane & 3) * 8;

    floatx4 acc[4][4];
    #pragma unroll
    for (int i = 0; i < 4; i++)
        #pragma unroll
        for (int j = 0; j < 4; j++) acc[i][j] = (floatx4)0.0f;

    for (int k0 = 0; k0 < 1024; k0 += 32) {
        #pragma unroll
        for (int t = 0; t < 2; t++) {
            const int rbase = wave * 32 + t * 16;       // wave-uniform
            const int r = rbase + lrow;
            async16(A  + (size_t)(bm + r) * 1024 + k0 + lcol, &As[rbase * 32]);
            async16(Bt + (size_t)(bn + r) * 1024 + k0 + lcol, &Bs[rbase * 32]);
        }
        __syncthreads();
        short8 af[4], bfr[4];
        #pragma unroll
        for (int i = 0; i < 4; i++)
            af[i] = *(const short8*)&As[(wr * 64 + i * 16 + lr) * 32 + quad * 8];
        #pragma unroll
        for (int j = 0; j < 4; j++)
            bfr[j] = *(const short8*)&Bs[(wc * 64 + j * 16 + lr) * 32 + quad * 8];
        #pragma unroll
        for (int i = 0; i < 4; i++)
            #pragma unroll
            for (int j = 0; j < 4; j++)
                acc[i][j] = __builtin_amdgcn_mfma_f32_16x16x32_bf16(af[i], bfr[j], acc[i][j], 0, 0, 0);
        __syncthreads();
    }

    const int part = bn >> 10;
    unsigned short* __restrict__ dstb = (part == 0) ? qb : ((part == 1) ? kb : vb);
    const float sc = (part == 0) ? QSCALE : 1.0f;
    const int dbase = bn & 1023;
    #pragma unroll
    for (int i = 0; i < 4; i++)
        #pragma unroll
        for (int j = 0; j < 4; j++)
            #pragma unroll
            for (int r = 0; r < 4; r++) {
                int row = bm + wr * 64 + i * 16 + quad * 4 + r;
                int d   = dbase + wc * 64 + j * 16 + lr;
                int b = row >> 11, l = row & 2047;
                int flat = (l << 10) | d;
                int h = flat >> 17;
                int rem = flat & 131071;
                int l2 = rem >> 6, kk = rem & 63;
                dstb[((size_t)(b * 16 + h) * 2048 + l2) * 64 + kk] = f2bf(acc[i][j][r] * sc);
            }
}

__global__ __launch_bounds__(256) void out_gemm(
    const unsigned short* __restrict__ A, const unsigned short* __restrict__ Bt,
    float* __restrict__ C)
{
    __shared__ __align__(16) unsigned short As[128 * 32];
    __shared__ __align__(16) unsigned short Bs[128 * 32];
    const int tid = threadIdx.x, wave = tid >> 6, lane = tid & 63;
    const int quad = lane >> 4, lr = lane & 15;
    const int wr = wave >> 1, wc = wave & 1;
    const int bm = blockIdx.y * 128, bn = blockIdx.x * 128;
    const int lrow = lane >> 2, lcol = (lane & 3) * 8;

    floatx4 acc[4][4];
    #pragma unroll
    for (int i = 0; i < 4; i++)
        #pragma unroll
        for (int j = 0; j < 4; j++) acc[i][j] = (floatx4)0.0f;

    for (int k0 = 0; k0 < 1024; k0 += 32) {
        #pragma unroll
        for (int t = 0; t < 2; t++) {
            const int rbase = wave * 32 + t * 16;
            const int r = rbase + lrow;
            async16(A  + (size_t)(bm + r) * 1024 + k0 + lcol, &As[rbase * 32]);
            async16(Bt + (size_t)(bn + r) * 1024 + k0 + lcol, &Bs[rbase * 32]);
        }
        __syncthreads();
        short8 af[4], bfr[4];
        #pragma unroll
        for (int i = 0; i < 4; i++)
            af[i] = *(const short8*)&As[(wr * 64 + i * 16 + lr) * 32 + quad * 8];
        #pragma unroll
        for (int j = 0; j < 4; j++)
            bfr[j] = *(const short8*)&Bs[(wc * 64 + j * 16 + lr) * 32 + quad * 8];
        #pragma unroll
        for (int i = 0; i < 4; i++)
            #pragma unroll
            for (int j = 0; j < 4; j++)
                acc[i][j] = __builtin_amdgcn_mfma_f32_16x16x32_bf16(af[i], bfr[j], acc[i][j], 0, 0, 0);
        __syncthreads();
    }
    #pragma unroll
    for (int i = 0; i < 4; i++)
        #pragma unroll
        for (int j = 0; j < 4; j++)
            #pragma unroll
            for (int r = 0; r < 4; r++) {
                int row = bm + wr * 64 + i * 16 + quad * 4 + r;
                int col = bn + wc * 64 + j * 16 + lr;
                C[(size_t)row * 1024 + col] = acc[i][j][r];
            }
}

// ---------------------------------------------------------------------------
// attn_denom: block = (b, 64 l x 64 m). Loops 16 heads; Q/K tiles staged
// swizzled in LDS; next head's tiles prefetched into registers. Stores
// reciprocal denom in transposed-C-tile order drpT[b][mt][lt][256].
// ---------------------------------------------------------------------------
__global__ __launch_bounds__(256, 4) void attn_denom(
    const unsigned short* __restrict__ qb, const unsigned short* __restrict__ kb,
    unsigned short* __restrict__ drpT)
{
    __shared__ __align__(16) unsigned short Qs[64 * 64];
    __shared__ __align__(16) unsigned short Ks[64 * 64];
    const int tid = threadIdx.x, wave = tid >> 6, lane = tid & 63;
    const int quad = lane >> 4, lr = lane & 15;
    const int M0 = blockIdx.x * 64, L0 = blockIdx.y * 64, b = blockIdx.z;
    const int srow = tid >> 3, sblk = tid & 7;       // rows srow, srow+32
    const int sphys = (sblk ^ (srow & 7)) * 8;

    floatx4 e[4];
    #pragma unroll
    for (int i = 0; i < 4; i++) e[i] = (floatx4)0.0f;

    {
        const size_t hb = ((size_t)(b * 16)) << 17;
        short8 q0 = *(const short8*)(qb + hb + (size_t)(L0 + srow) * 64 + sblk * 8);
        short8 q1 = *(const short8*)(qb + hb + (size_t)(L0 + srow + 32) * 64 + sblk * 8);
        short8 k0 = *(const short8*)(kb + hb + (size_t)(M0 + srow) * 64 + sblk * 8);
        short8 k1 = *(const short8*)(kb + hb + (size_t)(M0 + srow + 32) * 64 + sblk * 8);
        *(short8*)&Qs[srow * 64 + sphys] = q0;
        *(short8*)&Qs[(srow + 32) * 64 + sphys] = q1;
        *(short8*)&Ks[srow * 64 + sphys] = k0;
        *(short8*)&Ks[(srow + 32) * 64 + sphys] = k1;
    }
    __syncthreads();

    for (int h = 0; h < 16; h++) {
        short8 qn0, qn1, kn0, kn1;
        if (h < 15) {
            const size_t hb = ((size_t)(b * 16 + h + 1)) << 17;
            qn0 = *(const short8*)(qb + hb + (size_t)(L0 + srow) * 64 + sblk * 8);
            qn1 = *(const short8*)(qb + hb + (size_t)(L0 + srow + 32) * 64 + sblk * 8);
            kn0 = *(const short8*)(kb + hb + (size_t)(M0 + srow) * 64 + sblk * 8);
            kn1 = *(const short8*)(kb + hb + (size_t)(M0 + srow + 32) * 64 + sblk * 8);
        }
        const int rq = wave * 16 + lr;
        short8 qf0 = *(const short8*)&Qs[rq * 64 + ((quad) ^ (lr & 7)) * 8];
        short8 qf1 = *(const short8*)&Qs[rq * 64 + ((4 + quad) ^ (lr & 7)) * 8];
        #pragma unroll
        for (int mt = 0; mt < 4; mt++) {
            const int rk = mt * 16 + lr;
            short8 kf0 = *(const short8*)&Ks[rk * 64 + ((quad) ^ (lr & 7)) * 8];
            short8 kf1 = *(const short8*)&Ks[rk * 64 + ((4 + quad) ^ (lr & 7)) * 8];
            floatx4 s = (floatx4)0.0f;
            s = __builtin_amdgcn_mfma_f32_16x16x32_bf16(kf0, qf0, s, 0, 0, 0);
            s = __builtin_amdgcn_mfma_f32_16x16x32_bf16(kf1, qf1, s, 0, 0, 0);
            e[mt][0] += __builtin_amdgcn_exp2f(s[0]);
            e[mt][1] += __builtin_amdgcn_exp2f(s[1]);
            e[mt][2] += __builtin_amdgcn_exp2f(s[2]);
            e[mt][3] += __builtin_amdgcn_exp2f(s[3]);
        }
        __syncthreads();
        if (h < 15) {
            *(short8*)&Qs[srow * 64 + sphys] = qn0;
            *(short8*)&Qs[(srow + 32) * 64 + sphys] = qn1;
            *(short8*)&Ks[srow * 64 + sphys] = kn0;
            *(short8*)&Ks[(srow + 32) * 64 + sphys] = kn1;
            __syncthreads();
        }
    }
    #pragma unroll
    for (int mt = 0; mt < 4; mt++) {
        float r0 = __builtin_amdgcn_rcpf(e[mt][0]);
        float r1 = __builtin_amdgcn_rcpf(e[mt][1]);
        float r2 = __builtin_amdgcn_rcpf(e[mt][2]);
        float r3 = __builtin_amdgcn_rcpf(e[mt][3]);
        uint2 o;
        o.x = pack2bf(r0, r1);
        o.y = pack2bf(r2, r3);
        int mtg = (M0 >> 4) + mt;
        int ltg = (L0 >> 4) + wave;
        *(uint2*)(drpT + ((((size_t)b * 128 + mtg) * 128 + ltg) << 8) + lane * 4) = o;
    }
}

// ---------------------------------------------------------------------------
// attn_pv (barrier-free): block = (b, h, 128 l). The per-step __syncthreads
// of the previous version existed only for the shared-LDS K staging; its
// implied vmcnt(0)/lgkmcnt(0) drain of all in-flight loads (V frags, drp
// prefetch) was the dominant stall (MfmaUtil 14%, VALUBusy 25%, HBM 13%).
// Now K fragments are read per-wave straight from global (de-swizzled
// address of the old LDS read), reloaded for step t+1 right after their
// last use in step t. Ps stays wave-private LDS (16 KB). No __syncthreads
// in the main loop; waves run fully independently.
// VGPR budget: qf 16 + oacc 32 + kf 32 + du 16 + vf0/vf1 32 + temps ~= 150;
// __launch_bounds__(256,3) caps at ~170 so the allocator never spills.
// ---------------------------------------------------------------------------
__global__ __launch_bounds__(256, 3) void attn_pv(
    const unsigned short* __restrict__ qb, const unsigned short* __restrict__ kb,
    const unsigned short* __restrict__ vbt, const unsigned short* __restrict__ drpT,
    unsigned short* __restrict__ cb)
{
    __shared__ __align__(16) unsigned short Ps[128 * 64];    // 16 KB
    const int tid = threadIdx.x, wave = tid >> 6, lane = tid & 63;
    const int quad = lane >> 4, lr = lane & 15;
    const int L0 = blockIdx.x * 128, h = blockIdx.y, b = blockIdx.z;
    const size_t head = (size_t)(b * 16 + h);
    const unsigned short* qbase = qb + (head << 17);
    const unsigned short* kbase = kb + (head << 17);
    const unsigned short* vtb   = vbt + (head << 17);        // [64][2048]
    const int e7 = lr & 7;
    // drp base for this wave's two l-tiles (ltg = (L0>>4)+wave*2 + j)
    const unsigned short* dbase = drpT + (((size_t)b * 128 * 128 + ((L0 >> 4) + wave * 2)) << 8) + lane * 4;

    // Q B-fragments (rows L0 + wave*32 + j*16 + lr), loaded once
    short8 qf[2][2];
    #pragma unroll
    for (int j = 0; j < 2; j++) {
        const unsigned short* qr = qbase + (size_t)(L0 + wave * 32 + j * 16 + lr) * 64;
        qf[j][0] = *(const short8*)(qr + quad * 8);
        qf[j][1] = *(const short8*)(qr + 32 + quad * 8);
    }

    floatx4 oacc[2][4];
    #pragma unroll
    for (int i = 0; i < 2; i++)
        #pragma unroll
        for (int j = 0; j < 4; j++) oacc[i][j] = (floatx4)0.0f;

    // per-lane K fragment base: row lr, col quad*8 (row mt*16 added per use)
    const unsigned short* kfp = kbase + (size_t)lr * 64 + quad * 8;

    // prologue: K frags and drp for t=0 (one full step of latency cover)
    short8 kf[4][2];
    #pragma unroll
    for (int mt = 0; mt < 4; mt++) {
        kf[mt][0] = *(const short8*)(kfp + (size_t)(mt * 16) * 64);
        kf[mt][1] = *(const short8*)(kfp + (size_t)(mt * 16) * 64 + 32);
    }
    uint2 du[4][2];
    #pragma unroll
    for (int mt = 0; mt < 4; mt++)
        #pragma unroll
        for (int j = 0; j < 2; j++)
            du[mt][j] = *(const uint2*)(dbase + ((size_t)mt << 15) + (j << 8));

    for (int t = 0; t < 32; t++) {
        const int M0 = t * 64;
        // ---- V frags, first k-half (consumed in PV f=0) ----
        short8 vf0[4], vf1[4];
        #pragma unroll
        for (int j2 = 0; j2 < 4; j2++)
            vf0[j2] = *(const short8*)(vtb + (size_t)(j2 * 16 + lr) * 2048 + M0 + quad * 8);

        // ---- S phase: S^T tiles (mt 0..3) x (j 0..1), P -> wave-private LDS ----
        #pragma unroll
        for (int mt = 0; mt < 4; mt++) {
            short8 kf0 = kf[mt][0], kf1 = kf[mt][1];
            #pragma unroll
            for (int j = 0; j < 2; j++) {
                uint2 duv = du[mt][j];
                floatx4 s = (floatx4)0.0f;
                s = __builtin_amdgcn_mfma_f32_16x16x32_bf16(kf0, qf[j][0], s, 0, 0, 0);
                s = __builtin_amdgcn_mfma_f32_16x16x32_bf16(kf1, qf[j][1], s, 0, 0, 0);
                float r0 = __uint_as_float(duv.x << 16);
                float r1 = __uint_as_float(duv.x & 0xffff0000u);
                float r2 = __uint_as_float(duv.y << 16);
                float r3 = __uint_as_float(duv.y & 0xffff0000u);
                float p0 = __builtin_amdgcn_exp2f(s[0]) * r0;
                float p1 = __builtin_amdgcn_exp2f(s[1]) * r1;
                float p2 = __builtin_amdgcn_exp2f(s[2]) * r2;
                float p3 = __builtin_amdgcn_exp2f(s[3]) * r3;
                uint2 o;
                o.x = pack2bf(p0, p1);
                o.y = pack2bf(p2, p3);
                const int l_loc = wave * 32 + j * 16 + lr;
                const int lb16 = mt * 2 + (quad >> 1);
                *(uint2*)&Ps[l_loc * 64 + (lb16 ^ e7) * 8 + (quad & 1) * 4] = o;
            }
            // reload kf[mt] for step t+1 right after its last use (full-step
            // cover). t=31 overreads past this head's K: lands inside the
            // workspace (next head / vbt), value unused -> safe.
            kf[mt][0] = *(const short8*)(kfp + (size_t)(M0 + 64 + mt * 16) * 64);
            kf[mt][1] = *(const short8*)(kfp + (size_t)(M0 + 64 + mt * 16) * 64 + 32);
            if (mt == 1) {
                // mid-S issue of second-half V frags (consumed in PV f=1)
                #pragma unroll
                for (int j2 = 0; j2 < 4; j2++)
                    vf1[j2] = *(const short8*)(vtb + (size_t)(j2 * 16 + lr) * 2048 + M0 + 32 + quad * 8);
            }
        }
        // ---- prefetch next step's drp (t=31 overread is in-workspace, unused) ----
        #pragma unroll
        for (int mt = 0; mt < 4; mt++)
            #pragma unroll
            for (int j = 0; j < 2; j++)
                du[mt][j] = *(const uint2*)(dbase + (((size_t)((t + 1) * 4 + mt)) << 15) + (j << 8));

        // ---- PV phase: wave-private P A-frags + register V frags ----
        #pragma unroll
        for (int f = 0; f < 2; f++) {
            short8 pf[2];
            #pragma unroll
            for (int i2 = 0; i2 < 2; i2++) {
                const int lrow = wave * 32 + i2 * 16 + lr;
                pf[i2] = *(const short8*)&Ps[lrow * 64 + ((f * 4 + quad) ^ e7) * 8];
            }
            #pragma unroll
            for (int j2 = 0; j2 < 4; j2++)
                #pragma unroll
                for (int i2 = 0; i2 < 2; i2++)
                    oacc[i2][j2] = __builtin_amdgcn_mfma_f32_16x16x32_bf16(
                        pf[i2], (f == 0) ? vf0[j2] : vf1[j2], oacc[i2][j2], 0, 0, 0);
        }
    }
    // epilogue: concat layout cb[b*2048 + l][h*64 + n]
    #pragma unroll
    for (int i2 = 0; i2 < 2; i2++)
        #pragma unroll
        for (int j2 = 0; j2 < 4; j2++)
            #pragma unroll
            for (int r = 0; r < 4; r++) {
                int row = L0 + wave * 32 + i2 * 16 + quad * 4 + r;
                int col = h * 64 + j2 * 16 + lr;
                cb[(size_t)(b * 2048 + row) * 1024 + col] = f2bf(oacc[i2][j2][r]);
            }
}

extern "C" void kernel_launch(void* const* d_in, const int* in_sizes, int n_in,
                              void* d_out, int out_size, void* d_ws, size_t ws_size,
                              hipStream_t stream) {
    const float* x    = (const float*)d_in[0];   // [4,2048,1024]
    const float* wqkv = (const float*)d_in[1];   // [1024,3072]
    const float* wo   = (const float*)d_in[2];   // [1024,1024]
    float* out = (float*)d_out;                  // [4,2048,1024] fp32

    // workspace: 100,663,296 bytes with overlays
    unsigned short* W = (unsigned short*)d_ws;
    unsigned short* qb   = W;                    // [4,16,2048,64] pre-scaled Q
    unsigned short* kb   = W + 8388608;          // [4,16,2048,64]
    unsigned short* vbt  = W + 16777216;         // [4,16,64,2048] V^T
    unsigned short* drpT = W + 25165824;         // [4][128mt][128lt][256] recip denom
    unsigned short* cb   = W + 41943040;         // [8192,1024] concat
    // overlays (lifetime-disjoint):
    unsigned short* xb    = drpT;                // bf16 x   (dead before denom)
    unsigned short* wqkvT = drpT + 8388608;      // bf16 wqkv^T [3072][1024]
    unsigned short* vb    = cb;                  // V row-major (dead before pv)
    unsigned short* woT   = drpT;                // bf16 wo^T [1024][1024] (after pv)

    cvt_bf16  <<<4096, 256, 0, stream>>>(x, xb, 1048576);
    tcvt      <<<dim3(48, 16), 256, 0, stream>>>(wqkv, wqkvT, 1024, 3072);
    qkv_gemm  <<<dim3(24, 64), 256, 0, stream>>>(xb, wqkvT, qb, kb, vb);
    vtrans    <<<dim3(32, 64), 256, 0, stream>>>(vb, vbt);
    attn_denom<<<dim3(32, 32, 4), 256, 0, stream>>>(qb, kb, drpT);
    attn_pv   <<<dim3(16, 16, 4), 256, 0, stream>>>(qb, kb, vbt, drpT, cb);
    tcvt      <<<dim3(16, 16), 256, 0, stream>>>(wo, woT, 1024, 1024);
    out_gemm  <<<dim3(8, 64), 256, 0, stream>>>(cb, woT, out);
}

// Round 2
// 527.337 us; speedup vs baseline: 1.0535x; 1.0535x over previous
//
#include <hip/hip_runtime.h>
#include <hip/hip_bf16.h>
#include <stdint.h>

typedef __attribute__((ext_vector_type(8))) short short8;
typedef __attribute__((ext_vector_type(4))) float floatx4;

// Q pre-scale: 0.125 (1/sqrt(K)) * log2(e), so exp(s/8) == exp2(q'.k)
#define QSCALE 0.18033688f

__device__ __forceinline__ unsigned short f2bf(float f) {
    unsigned int u = __float_as_uint(f);
    u += 0x7fffu + ((u >> 16) & 1u);
    return (unsigned short)(u >> 16);
}
__device__ __forceinline__ unsigned int pack2bf(float a, float b) {
    __hip_bfloat162 h = __float22bfloat162_rn(make_float2(a, b));
    return *reinterpret_cast<unsigned int*>(&h);
}

// async global->LDS, 16B per lane; LDS dst must be wave-uniform base + lane*16
__device__ __forceinline__ void async16(const void* g, void* l) {
    __builtin_amdgcn_global_load_lds(
        (const __attribute__((address_space(1))) unsigned int*)g,
        (__attribute__((address_space(3))) unsigned int*)l, 16, 0, 0);
}

// ---------------------------------------------------------------------------
// cvt: fp32 -> bf16, 8 elements/thread
// ---------------------------------------------------------------------------
__global__ __launch_bounds__(256) void cvt_bf16(const float* __restrict__ src,
                                                unsigned short* __restrict__ dst, int n8) {
    int i = blockIdx.x * 256 + threadIdx.x;
    if (i >= n8) return;
    const float4 a = ((const float4*)src)[2 * i];
    const float4 b = ((const float4*)src)[2 * i + 1];
    ushort4 lo, hi;
    lo.x = f2bf(a.x); lo.y = f2bf(a.y); lo.z = f2bf(a.z); lo.w = f2bf(a.w);
    hi.x = f2bf(b.x); hi.y = f2bf(b.y); hi.z = f2bf(b.z); hi.w = f2bf(b.w);
    ((ushort4*)dst)[2 * i] = lo;
    ((ushort4*)dst)[2 * i + 1] = hi;
}

// ---------------------------------------------------------------------------
// tcvt: fp32 [R][C] -> bf16 [C][R]  (64x64 tiles via LDS)
// ---------------------------------------------------------------------------
__global__ __launch_bounds__(256) void tcvt(const float* __restrict__ src,
                                            unsigned short* __restrict__ dst, int R, int C) {
    __shared__ unsigned short t[64][72];
    const int tid = threadIdx.x;
    const int r0 = blockIdx.y * 64, c0 = blockIdx.x * 64;
    #pragma unroll
    for (int it = 0; it < 4; it++) {
        int idx = it * 256 + tid;
        int rr = idx >> 4, cc = (idx & 15) * 4;
        float4 v = *(const float4*)(src + (size_t)(r0 + rr) * C + c0 + cc);
        t[cc + 0][rr] = f2bf(v.x);
        t[cc + 1][rr] = f2bf(v.y);
        t[cc + 2][rr] = f2bf(v.z);
        t[cc + 3][rr] = f2bf(v.w);
    }
    __syncthreads();
    #pragma unroll
    for (int it = 0; it < 2; it++) {
        int idx = it * 256 + tid;
        int cc = idx >> 3, r8 = (idx & 7) * 8;
        short8 v = *(const short8*)&t[cc][r8];
        *(short8*)(dst + (size_t)(c0 + cc) * R + r0 + r8) = v;
    }
}

// ---------------------------------------------------------------------------
// vtrans: vb[bh][2048][64] -> vbt[bh][64][2048]  (64x64 tiles via LDS)
// ---------------------------------------------------------------------------
__global__ __launch_bounds__(256) void vtrans(const unsigned short* __restrict__ vb,
                                              unsigned short* __restrict__ vbt) {
    __shared__ unsigned short t[64][72];
    const int tid = threadIdx.x;
    const int bh = blockIdx.y, m0 = blockIdx.x * 64;
    const unsigned short* src = vb + ((size_t)bh * 2048 + m0) * 64;
    unsigned short* dst = vbt + ((size_t)bh << 17) + m0;
    union { short8 v; unsigned short u[8]; } tmp;
    #pragma unroll
    for (int it = 0; it < 2; it++) {
        int idx = it * 256 + tid;
        int m = idx >> 3, c8 = (idx & 7) * 8;
        tmp.v = *(const short8*)(src + (size_t)m * 64 + c8);
        #pragma unroll
        for (int j = 0; j < 8; j++) t[c8 + j][m] = tmp.u[j];
    }
    __syncthreads();
    #pragma unroll
    for (int it = 0; it < 2; it++) {
        int idx = it * 256 + tid;
        int k = idx >> 3, c8 = (idx & 7) * 8;
        short8 v = *(const short8*)&t[k][c8];
        *(short8*)(dst + (size_t)k * 2048 + c8) = v;
    }
}

// ---------------------------------------------------------------------------
// qkv_gemm (128x128 tile, BK=32) with async global->LDS staging (16B/lane).
// ---------------------------------------------------------------------------
__global__ __launch_bounds__(256) void qkv_gemm(
    const unsigned short* __restrict__ A, const unsigned short* __restrict__ Bt,
    unsigned short* __restrict__ qb, unsigned short* __restrict__ kb,
    unsigned short* __restrict__ vb)
{
    __shared__ __align__(16) unsigned short As[128 * 32];
    __shared__ __align__(16) unsigned short Bs[128 * 32];
    const int tid = threadIdx.x, wave = tid >> 6, lane = tid & 63;
    const int quad = lane >> 4, lr = lane & 15;
    const int wr = wave >> 1, wc = wave & 1;
    const int bm = blockIdx.y * 128, bn = blockIdx.x * 128;
    const int lrow = lane >> 2, lcol = (lane & 3) * 8;

    floatx4 acc[4][4];
    #pragma unroll
    for (int i = 0; i < 4; i++)
        #pragma unroll
        for (int j = 0; j < 4; j++) acc[i][j] = (floatx4)0.0f;

    for (int k0 = 0; k0 < 1024; k0 += 32) {
        #pragma unroll
        for (int t = 0; t < 2; t++) {
            const int rbase = wave * 32 + t * 16;       // wave-uniform
            const int r = rbase + lrow;
            async16(A  + (size_t)(bm + r) * 1024 + k0 + lcol, &As[rbase * 32]);
            async16(Bt + (size_t)(bn + r) * 1024 + k0 + lcol, &Bs[rbase * 32]);
        }
        __syncthreads();
        short8 af[4], bfr[4];
        #pragma unroll
        for (int i = 0; i < 4; i++)
            af[i] = *(const short8*)&As[(wr * 64 + i * 16 + lr) * 32 + quad * 8];
        #pragma unroll
        for (int j = 0; j < 4; j++)
            bfr[j] = *(const short8*)&Bs[(wc * 64 + j * 16 + lr) * 32 + quad * 8];
        #pragma unroll
        for (int i = 0; i < 4; i++)
            #pragma unroll
            for (int j = 0; j < 4; j++)
                acc[i][j] = __builtin_amdgcn_mfma_f32_16x16x32_bf16(af[i], bfr[j], acc[i][j], 0, 0, 0);
        __syncthreads();
    }

    const int part = bn >> 10;
    unsigned short* __restrict__ dstb = (part == 0) ? qb : ((part == 1) ? kb : vb);
    const float sc = (part == 0) ? QSCALE : 1.0f;
    const int dbase = bn & 1023;
    #pragma unroll
    for (int i = 0; i < 4; i++)
        #pragma unroll
        for (int j = 0; j < 4; j++)
            #pragma unroll
            for (int r = 0; r < 4; r++) {
                int row = bm + wr * 64 + i * 16 + quad * 4 + r;
                int d   = dbase + wc * 64 + j * 16 + lr;
                int b = row >> 11, l = row & 2047;
                int flat = (l << 10) | d;
                int h = flat >> 17;
                int rem = flat & 131071;
                int l2 = rem >> 6, kk = rem & 63;
                dstb[((size_t)(b * 16 + h) * 2048 + l2) * 64 + kk] = f2bf(acc[i][j][r] * sc);
            }
}

__global__ __launch_bounds__(256) void out_gemm(
    const unsigned short* __restrict__ A, const unsigned short* __restrict__ Bt,
    float* __restrict__ C)
{
    __shared__ __align__(16) unsigned short As[128 * 32];
    __shared__ __align__(16) unsigned short Bs[128 * 32];
    const int tid = threadIdx.x, wave = tid >> 6, lane = tid & 63;
    const int quad = lane >> 4, lr = lane & 15;
    const int wr = wave >> 1, wc = wave & 1;
    const int bm = blockIdx.y * 128, bn = blockIdx.x * 128;
    const int lrow = lane >> 2, lcol = (lane & 3) * 8;

    floatx4 acc[4][4];
    #pragma unroll
    for (int i = 0; i < 4; i++)
        #pragma unroll
        for (int j = 0; j < 4; j++) acc[i][j] = (floatx4)0.0f;

    for (int k0 = 0; k0 < 1024; k0 += 32) {
        #pragma unroll
        for (int t = 0; t < 2; t++) {
            const int rbase = wave * 32 + t * 16;
            const int r = rbase + lrow;
            async16(A  + (size_t)(bm + r) * 1024 + k0 + lcol, &As[rbase * 32]);
            async16(Bt + (size_t)(bn + r) * 1024 + k0 + lcol, &Bs[rbase * 32]);
        }
        __syncthreads();
        short8 af[4], bfr[4];
        #pragma unroll
        for (int i = 0; i < 4; i++)
            af[i] = *(const short8*)&As[(wr * 64 + i * 16 + lr) * 32 + quad * 8];
        #pragma unroll
        for (int j = 0; j < 4; j++)
            bfr[j] = *(const short8*)&Bs[(wc * 64 + j * 16 + lr) * 32 + quad * 8];
        #pragma unroll
        for (int i = 0; i < 4; i++)
            #pragma unroll
            for (int j = 0; j < 4; j++)
                acc[i][j] = __builtin_amdgcn_mfma_f32_16x16x32_bf16(af[i], bfr[j], acc[i][j], 0, 0, 0);
        __syncthreads();
    }
    #pragma unroll
    for (int i = 0; i < 4; i++)
        #pragma unroll
        for (int j = 0; j < 4; j++)
            #pragma unroll
            for (int r = 0; r < 4; r++) {
                int row = bm + wr * 64 + i * 16 + quad * 4 + r;
                int col = bn + wc * 64 + j * 16 + lr;
                C[(size_t)row * 1024 + col] = acc[i][j][r];
            }
}

// ---------------------------------------------------------------------------
// attn_denom: block = (b, 64 l x 64 m). Loops 16 heads; Q/K tiles staged
// swizzled in LDS; next head's tiles prefetched into registers. Stores
// reciprocal denom in transposed-C-tile order drpT[b][mt][lt][256].
// ---------------------------------------------------------------------------
__global__ __launch_bounds__(256, 4) void attn_denom(
    const unsigned short* __restrict__ qb, const unsigned short* __restrict__ kb,
    unsigned short* __restrict__ drpT)
{
    __shared__ __align__(16) unsigned short Qs[64 * 64];
    __shared__ __align__(16) unsigned short Ks[64 * 64];
    const int tid = threadIdx.x, wave = tid >> 6, lane = tid & 63;
    const int quad = lane >> 4, lr = lane & 15;
    const int M0 = blockIdx.x * 64, L0 = blockIdx.y * 64, b = blockIdx.z;
    const int srow = tid >> 3, sblk = tid & 7;       // rows srow, srow+32
    const int sphys = (sblk ^ (srow & 7)) * 8;

    floatx4 e[4];
    #pragma unroll
    for (int i = 0; i < 4; i++) e[i] = (floatx4)0.0f;

    {
        const size_t hb = ((size_t)(b * 16)) << 17;
        short8 q0 = *(const short8*)(qb + hb + (size_t)(L0 + srow) * 64 + sblk * 8);
        short8 q1 = *(const short8*)(qb + hb + (size_t)(L0 + srow + 32) * 64 + sblk * 8);
        short8 k0 = *(const short8*)(kb + hb + (size_t)(M0 + srow) * 64 + sblk * 8);
        short8 k1 = *(const short8*)(kb + hb + (size_t)(M0 + srow + 32) * 64 + sblk * 8);
        *(short8*)&Qs[srow * 64 + sphys] = q0;
        *(short8*)&Qs[(srow + 32) * 64 + sphys] = q1;
        *(short8*)&Ks[srow * 64 + sphys] = k0;
        *(short8*)&Ks[(srow + 32) * 64 + sphys] = k1;
    }
    __syncthreads();

    for (int h = 0; h < 16; h++) {
        short8 qn0, qn1, kn0, kn1;
        if (h < 15) {
            const size_t hb = ((size_t)(b * 16 + h + 1)) << 17;
            qn0 = *(const short8*)(qb + hb + (size_t)(L0 + srow) * 64 + sblk * 8);
            qn1 = *(const short8*)(qb + hb + (size_t)(L0 + srow + 32) * 64 + sblk * 8);
            kn0 = *(const short8*)(kb + hb + (size_t)(M0 + srow) * 64 + sblk * 8);
            kn1 = *(const short8*)(kb + hb + (size_t)(M0 + srow + 32) * 64 + sblk * 8);
        }
        const int rq = wave * 16 + lr;
        short8 qf0 = *(const short8*)&Qs[rq * 64 + ((quad) ^ (lr & 7)) * 8];
        short8 qf1 = *(const short8*)&Qs[rq * 64 + ((4 + quad) ^ (lr & 7)) * 8];
        #pragma unroll
        for (int mt = 0; mt < 4; mt++) {
            const int rk = mt * 16 + lr;
            short8 kf0 = *(const short8*)&Ks[rk * 64 + ((quad) ^ (lr & 7)) * 8];
            short8 kf1 = *(const short8*)&Ks[rk * 64 + ((4 + quad) ^ (lr & 7)) * 8];
            floatx4 s = (floatx4)0.0f;
            s = __builtin_amdgcn_mfma_f32_16x16x32_bf16(kf0, qf0, s, 0, 0, 0);
            s = __builtin_amdgcn_mfma_f32_16x16x32_bf16(kf1, qf1, s, 0, 0, 0);
            e[mt][0] += __builtin_amdgcn_exp2f(s[0]);
            e[mt][1] += __builtin_amdgcn_exp2f(s[1]);
            e[mt][2] += __builtin_amdgcn_exp2f(s[2]);
            e[mt][3] += __builtin_amdgcn_exp2f(s[3]);
        }
        __syncthreads();
        if (h < 15) {
            *(short8*)&Qs[srow * 64 + sphys] = qn0;
            *(short8*)&Qs[(srow + 32) * 64 + sphys] = qn1;
            *(short8*)&Ks[srow * 64 + sphys] = kn0;
            *(short8*)&Ks[(srow + 32) * 64 + sphys] = kn1;
            __syncthreads();
        }
    }
    #pragma unroll
    for (int mt = 0; mt < 4; mt++) {
        float r0 = __builtin_amdgcn_rcpf(e[mt][0]);
        float r1 = __builtin_amdgcn_rcpf(e[mt][1]);
        float r2 = __builtin_amdgcn_rcpf(e[mt][2]);
        float r3 = __builtin_amdgcn_rcpf(e[mt][3]);
        uint2 o;
        o.x = pack2bf(r0, r1);
        o.y = pack2bf(r2, r3);
        int mtg = (M0 >> 4) + mt;
        int ltg = (L0 >> 4) + wave;
        *(uint2*)(drpT + ((((size_t)b * 128 + mtg) * 128 + ltg) << 8) + lane * 4) = o;
    }
}

// ---------------------------------------------------------------------------
// attn_pv v3: R0 dataflow (LDS-staged double-buffered K, barrier-anchored),
// restructured for occupancy. Block = 64 l-rows (wave owns 16), grid 2048
// (XCD-swizzled so each XCD keeps 8 heads of one batch in its private L2).
// K staging now uses global_load_lds with pre-swizzled per-lane global source
// (XOR involution) into a linear LDS dest -> no register staging, no
// ds_writes, lower VGPR. LDS 24 KB (Ks 2x8 + Ps 8) -> 5-6 blocks/CU vs 3.4.
// setprio(1) wraps MFMA clusters (T5). One barrier per step, as in R0.
// ---------------------------------------------------------------------------
__global__ __launch_bounds__(256, 4) void attn_pv(
    const unsigned short* __restrict__ qb, const unsigned short* __restrict__ kb,
    const unsigned short* __restrict__ vbt, const unsigned short* __restrict__ drpT,
    unsigned short* __restrict__ cb)
{
    __shared__ __align__(16) unsigned short Ks[2][64 * 64];  // 2 x 8 KB
    __shared__ __align__(16) unsigned short Ps[64 * 64];     // 8 KB
    const int tid = threadIdx.x, wave = tid >> 6, lane = tid & 63;
    const int quad = lane >> 4, lr = lane & 15;
    // bijective XCD swizzle: 2048 blocks, XCD x gets swz range [x*256, x*256+256)
    // = (b = x/2, 8 heads, all 32 L-blocks) -> K/V of those heads L2-resident.
    const int flat = blockIdx.x;
    const int swz = (flat & 7) * 256 + (flat >> 3);
    const int L0 = (swz & 31) * 64;
    const int h = (swz >> 5) & 15;
    const int b = swz >> 9;
    const size_t head = (size_t)(b * 16 + h);
    const unsigned short* qbase = qb + (head << 17);
    const unsigned short* kbase = kb + (head << 17);
    const unsigned short* vtb   = vbt + (head << 17);        // [64][2048]
    const int e7 = lr & 7;
    // drp base for this wave's l-tile (ltg = (L0>>4)+wave)
    const unsigned short* dbase = drpT + (((size_t)b * 128 * 128 + (L0 >> 4) + wave) << 8) + lane * 4;

    // K async-stage: lane covers (row = 8*wave + (lane>>3), block = lane&7) of
    // the linear LDS dest; global source block pre-XOR'd by row&7 so the read
    // side's (quad ^ e7) swizzle sees the standard layout (rule-21 involution).
    const int klr = lane >> 3;
    const int ksw = (lane & 7) ^ klr;
    const unsigned short* ksrc0 = kbase + (size_t)(wave * 8 + klr) * 64 + ksw * 8;

    // Q B-fragments (rows L0 + wave*16 + lr), loaded once
    short8 qf0, qf1;
    {
        const unsigned short* qr = qbase + (size_t)(L0 + wave * 16 + lr) * 64;
        qf0 = *(const short8*)(qr + quad * 8);
        qf1 = *(const short8*)(qr + 32 + quad * 8);
    }

    floatx4 oacc[4];
    #pragma unroll
    for (int j = 0; j < 4; j++) oacc[j] = (floatx4)0.0f;

    // prologue: stage K(0); load drp(0)
    async16(ksrc0, &Ks[0][(wave * 8) * 64]);
    async16(ksrc0 + 32 * 64, &Ks[0][(32 + wave * 8) * 64]);
    uint2 du[4];
    #pragma unroll
    for (int mt = 0; mt < 4; mt++)
        du[mt] = *(const uint2*)(dbase + ((size_t)mt << 15));
    __syncthreads();

    for (int t = 0; t < 32; t++) {
        const int M0 = t * 64;
        // ---- issue async K(t+1) into the idle buffer (full step to land) ----
        if (t < 31) {
            const unsigned short* ks = ksrc0 + (size_t)(M0 + 64) * 64;
            unsigned short* kd = &Ks[(t + 1) & 1][0];
            async16(ks, kd + (wave * 8) * 64);
            async16(ks + 32 * 64, kd + (32 + wave * 8) * 64);
        }
        // ---- V frags, first k-half ----
        short8 vf0[4], vf1[4];
        #pragma unroll
        for (int j2 = 0; j2 < 4; j2++)
            vf0[j2] = *(const short8*)(vtb + (size_t)(j2 * 16 + lr) * 2048 + M0 + quad * 8);

        // ---- S phase: 4 S^T tiles, P -> wave-private LDS ----
        const unsigned short* ksp = &Ks[t & 1][0];
        #pragma unroll
        for (int mt = 0; mt < 4; mt++) {
            const int rk = mt * 16 + lr;
            short8 kf0 = *(const short8*)&ksp[rk * 64 + (quad ^ e7) * 8];
            short8 kf1 = *(const short8*)&ksp[rk * 64 + ((4 + quad) ^ e7) * 8];
            uint2 duv = du[mt];
            floatx4 s = (floatx4)0.0f;
            __builtin_amdgcn_s_setprio(1);
            s = __builtin_amdgcn_mfma_f32_16x16x32_bf16(kf0, qf0, s, 0, 0, 0);
            s = __builtin_amdgcn_mfma_f32_16x16x32_bf16(kf1, qf1, s, 0, 0, 0);
            __builtin_amdgcn_s_setprio(0);
            float r0 = __uint_as_float(duv.x << 16);
            float r1 = __uint_as_float(duv.x & 0xffff0000u);
            float r2 = __uint_as_float(duv.y << 16);
            float r3 = __uint_as_float(duv.y & 0xffff0000u);
            float p0 = __builtin_amdgcn_exp2f(s[0]) * r0;
            float p1 = __builtin_amdgcn_exp2f(s[1]) * r1;
            float p2 = __builtin_amdgcn_exp2f(s[2]) * r2;
            float p3 = __builtin_amdgcn_exp2f(s[3]) * r3;
            uint2 o;
            o.x = pack2bf(p0, p1);
            o.y = pack2bf(p2, p3);
            const int l_loc = wave * 16 + lr;
            const int lb16 = mt * 2 + (quad >> 1);
            *(uint2*)&Ps[l_loc * 64 + (lb16 ^ e7) * 8 + (quad & 1) * 4] = o;
            if (mt == 1) {
                // mid-S issue of second-half V frags (consumed in PV f=1)
                #pragma unroll
                for (int j2 = 0; j2 < 4; j2++)
                    vf1[j2] = *(const short8*)(vtb + (size_t)(j2 * 16 + lr) * 2048 + M0 + 32 + quad * 8);
            }
        }
        // ---- prefetch next step's drp (consumed next iteration) ----
        if (t < 31) {
            #pragma unroll
            for (int mt = 0; mt < 4; mt++)
                du[mt] = *(const uint2*)(dbase + (((size_t)((t + 1) * 4 + mt)) << 15));
        }
        // ---- PV phase: wave-private P A-frags + register V frags ----
        #pragma unroll
        for (int f = 0; f < 2; f++) {
            const int lrow = wave * 16 + lr;
            short8 pf = *(const short8*)&Ps[lrow * 64 + ((f * 4 + quad) ^ e7) * 8];
            __builtin_amdgcn_s_setprio(1);
            #pragma unroll
            for (int j2 = 0; j2 < 4; j2++)
                oacc[j2] = __builtin_amdgcn_mfma_f32_16x16x32_bf16(
                    pf, (f == 0) ? vf0[j2] : vf1[j2], oacc[j2], 0, 0, 0);
            __builtin_amdgcn_s_setprio(0);
        }
        // ---- single barrier per step (also drains async K(t+1)) ----
        if (t < 31) __syncthreads();
    }
    // epilogue: concat layout cb[b*2048 + l][h*64 + n]
    #pragma unroll
    for (int j2 = 0; j2 < 4; j2++)
        #pragma unroll
        for (int r = 0; r < 4; r++) {
            int row = L0 + wave * 16 + quad * 4 + r;
            int col = h * 64 + j2 * 16 + lr;
            cb[(size_t)(b * 2048 + row) * 1024 + col] = f2bf(oacc[j2][r]);
        }
}

extern "C" void kernel_launch(void* const* d_in, const int* in_sizes, int n_in,
                              void* d_out, int out_size, void* d_ws, size_t ws_size,
                              hipStream_t stream) {
    const float* x    = (const float*)d_in[0];   // [4,2048,1024]
    const float* wqkv = (const float*)d_in[1];   // [1024,3072]
    const float* wo   = (const float*)d_in[2];   // [1024,1024]
    float* out = (float*)d_out;                  // [4,2048,1024] fp32

    // workspace: 100,663,296 bytes with overlays
    unsigned short* W = (unsigned short*)d_ws;
    unsigned short* qb   = W;                    // [4,16,2048,64] pre-scaled Q
    unsigned short* kb   = W + 8388608;          // [4,16,2048,64]
    unsigned short* vbt  = W + 16777216;         // [4,16,64,2048] V^T
    unsigned short* drpT = W + 25165824;         // [4][128mt][128lt][256] recip denom
    unsigned short* cb   = W + 41943040;         // [8192,1024] concat
    // overlays (lifetime-disjoint):
    unsigned short* xb    = drpT;                // bf16 x   (dead before denom)
    unsigned short* wqkvT = drpT + 8388608;      // bf16 wqkv^T [3072][1024]
    unsigned short* vb    = cb;                  // V row-major (dead before pv)
    unsigned short* woT   = drpT;                // bf16 wo^T [1024][1024] (after pv)

    cvt_bf16  <<<4096, 256, 0, stream>>>(x, xb, 1048576);
    tcvt      <<<dim3(48, 16), 256, 0, stream>>>(wqkv, wqkvT, 1024, 3072);
    qkv_gemm  <<<dim3(24, 64), 256, 0, stream>>>(xb, wqkvT, qb, kb, vb);
    vtrans    <<<dim3(32, 64), 256, 0, stream>>>(vb, vbt);
    attn_denom<<<dim3(32, 32, 4), 256, 0, stream>>>(qb, kb, drpT);
    attn_pv   <<<2048, 256, 0, stream>>>(qb, kb, vbt, drpT, cb);
    tcvt      <<<dim3(16, 16), 256, 0, stream>>>(wo, woT, 1024, 1024);
    out_gemm  <<<dim3(8, 64), 256, 0, stream>>>(cb, woT, out);
}

// Round 3
// 358.597 us; speedup vs baseline: 1.5492x; 1.4706x over previous
//
#include <hip/hip_runtime.h>
#include <hip/hip_bf16.h>
#include <stdint.h>

typedef __attribute__((ext_vector_type(8))) short short8;
typedef __attribute__((ext_vector_type(4))) float floatx4;

// Q pre-scale: 0.125 (1/sqrt(K)) * log2(e), so exp(s/8) == exp2(q'.k)
#define QSCALE 0.18033688f

__device__ __forceinline__ unsigned short f2bf(float f) {
    unsigned int u = __float_as_uint(f);
    u += 0x7fffu + ((u >> 16) & 1u);
    return (unsigned short)(u >> 16);
}
__device__ __forceinline__ unsigned int pack2bf(float a, float b) {
    __hip_bfloat162 h = __float22bfloat162_rn(make_float2(a, b));
    return *reinterpret_cast<unsigned int*>(&h);
}

// async global->LDS, 16B per lane; LDS dst must be wave-uniform base + lane*16
__device__ __forceinline__ void async16(const void* g, void* l) {
    __builtin_amdgcn_global_load_lds(
        (const __attribute__((address_space(1))) unsigned int*)g,
        (__attribute__((address_space(3))) unsigned int*)l, 16, 0, 0);
}

// ---------------------------------------------------------------------------
// cvt: fp32 -> bf16, 8 elements/thread
// ---------------------------------------------------------------------------
__global__ __launch_bounds__(256) void cvt_bf16(const float* __restrict__ src,
                                                unsigned short* __restrict__ dst, int n8) {
    int i = blockIdx.x * 256 + threadIdx.x;
    if (i >= n8) return;
    const float4 a = ((const float4*)src)[2 * i];
    const float4 b = ((const float4*)src)[2 * i + 1];
    ushort4 lo, hi;
    lo.x = f2bf(a.x); lo.y = f2bf(a.y); lo.z = f2bf(a.z); lo.w = f2bf(a.w);
    hi.x = f2bf(b.x); hi.y = f2bf(b.y); hi.z = f2bf(b.z); hi.w = f2bf(b.w);
    ((ushort4*)dst)[2 * i] = lo;
    ((ushort4*)dst)[2 * i + 1] = hi;
}

// ---------------------------------------------------------------------------
// tcvt: fp32 [R][C] -> bf16 [C][R]  (64x64 tiles via LDS)
// ---------------------------------------------------------------------------
__global__ __launch_bounds__(256) void tcvt(const float* __restrict__ src,
                                            unsigned short* __restrict__ dst, int R, int C) {
    __shared__ unsigned short t[64][72];
    const int tid = threadIdx.x;
    const int r0 = blockIdx.y * 64, c0 = blockIdx.x * 64;
    #pragma unroll
    for (int it = 0; it < 4; it++) {
        int idx = it * 256 + tid;
        int rr = idx >> 4, cc = (idx & 15) * 4;
        float4 v = *(const float4*)(src + (size_t)(r0 + rr) * C + c0 + cc);
        t[cc + 0][rr] = f2bf(v.x);
        t[cc + 1][rr] = f2bf(v.y);
        t[cc + 2][rr] = f2bf(v.z);
        t[cc + 3][rr] = f2bf(v.w);
    }
    __syncthreads();
    #pragma unroll
    for (int it = 0; it < 2; it++) {
        int idx = it * 256 + tid;
        int cc = idx >> 3, r8 = (idx & 7) * 8;
        short8 v = *(const short8*)&t[cc][r8];
        *(short8*)(dst + (size_t)(c0 + cc) * R + r0 + r8) = v;
    }
}

// ---------------------------------------------------------------------------
// vtrans: vb[bh][2048][64] -> vbt[bh][64][2048]  (64x64 tiles via LDS)
// ---------------------------------------------------------------------------
__global__ __launch_bounds__(256) void vtrans(const unsigned short* __restrict__ vb,
                                              unsigned short* __restrict__ vbt) {
    __shared__ unsigned short t[64][72];
    const int tid = threadIdx.x;
    const int bh = blockIdx.y, m0 = blockIdx.x * 64;
    const unsigned short* src = vb + ((size_t)bh * 2048 + m0) * 64;
    unsigned short* dst = vbt + ((size_t)bh << 17) + m0;
    union { short8 v; unsigned short u[8]; } tmp;
    #pragma unroll
    for (int it = 0; it < 2; it++) {
        int idx = it * 256 + tid;
        int m = idx >> 3, c8 = (idx & 7) * 8;
        tmp.v = *(const short8*)(src + (size_t)m * 64 + c8);
        #pragma unroll
        for (int j = 0; j < 8; j++) t[c8 + j][m] = tmp.u[j];
    }
    __syncthreads();
    #pragma unroll
    for (int it = 0; it < 2; it++) {
        int idx = it * 256 + tid;
        int k = idx >> 3, c8 = (idx & 7) * 8;
        short8 v = *(const short8*)&t[k][c8];
        *(short8*)(dst + (size_t)k * 2048 + c8) = v;
    }
}

// ---------------------------------------------------------------------------
// qkv_gemm (128x128 tile, BK=32) with async global->LDS staging (16B/lane).
// ---------------------------------------------------------------------------
__global__ __launch_bounds__(256) void qkv_gemm(
    const unsigned short* __restrict__ A, const unsigned short* __restrict__ Bt,
    unsigned short* __restrict__ qb, unsigned short* __restrict__ kb,
    unsigned short* __restrict__ vb)
{
    __shared__ __align__(16) unsigned short As[128 * 32];
    __shared__ __align__(16) unsigned short Bs[128 * 32];
    const int tid = threadIdx.x, wave = tid >> 6, lane = tid & 63;
    const int quad = lane >> 4, lr = lane & 15;
    const int wr = wave >> 1, wc = wave & 1;
    const int bm = blockIdx.y * 128, bn = blockIdx.x * 128;
    const int lrow = lane >> 2, lcol = (lane & 3) * 8;

    floatx4 acc[4][4];
    #pragma unroll
    for (int i = 0; i < 4; i++)
        #pragma unroll
        for (int j = 0; j < 4; j++) acc[i][j] = (floatx4)0.0f;

    for (int k0 = 0; k0 < 1024; k0 += 32) {
        #pragma unroll
        for (int t = 0; t < 2; t++) {
            const int rbase = wave * 32 + t * 16;       // wave-uniform
            const int r = rbase + lrow;
            async16(A  + (size_t)(bm + r) * 1024 + k0 + lcol, &As[rbase * 32]);
            async16(Bt + (size_t)(bn + r) * 1024 + k0 + lcol, &Bs[rbase * 32]);
        }
        __syncthreads();
        short8 af[4], bfr[4];
        #pragma unroll
        for (int i = 0; i < 4; i++)
            af[i] = *(const short8*)&As[(wr * 64 + i * 16 + lr) * 32 + quad * 8];
        #pragma unroll
        for (int j = 0; j < 4; j++)
            bfr[j] = *(const short8*)&Bs[(wc * 64 + j * 16 + lr) * 32 + quad * 8];
        #pragma unroll
        for (int i = 0; i < 4; i++)
            #pragma unroll
            for (int j = 0; j < 4; j++)
                acc[i][j] = __builtin_amdgcn_mfma_f32_16x16x32_bf16(af[i], bfr[j], acc[i][j], 0, 0, 0);
        __syncthreads();
    }

    const int part = bn >> 10;
    unsigned short* __restrict__ dstb = (part == 0) ? qb : ((part == 1) ? kb : vb);
    const float sc = (part == 0) ? QSCALE : 1.0f;
    const int dbase = bn & 1023;
    #pragma unroll
    for (int i = 0; i < 4; i++)
        #pragma unroll
        for (int j = 0; j < 4; j++)
            #pragma unroll
            for (int r = 0; r < 4; r++) {
                int row = bm + wr * 64 + i * 16 + quad * 4 + r;
                int d   = dbase + wc * 64 + j * 16 + lr;
                int b = row >> 11, l = row & 2047;
                int flat = (l << 10) | d;
                int h = flat >> 17;
                int rem = flat & 131071;
                int l2 = rem >> 6, kk = rem & 63;
                dstb[((size_t)(b * 16 + h) * 2048 + l2) * 64 + kk] = f2bf(acc[i][j][r] * sc);
            }
}

__global__ __launch_bounds__(256) void out_gemm(
    const unsigned short* __restrict__ A, const unsigned short* __restrict__ Bt,
    float* __restrict__ C)
{
    __shared__ __align__(16) unsigned short As[128 * 32];
    __shared__ __align__(16) unsigned short Bs[128 * 32];
    const int tid = threadIdx.x, wave = tid >> 6, lane = tid & 63;
    const int quad = lane >> 4, lr = lane & 15;
    const int wr = wave >> 1, wc = wave & 1;
    const int bm = blockIdx.y * 128, bn = blockIdx.x * 128;
    const int lrow = lane >> 2, lcol = (lane & 3) * 8;

    floatx4 acc[4][4];
    #pragma unroll
    for (int i = 0; i < 4; i++)
        #pragma unroll
        for (int j = 0; j < 4; j++) acc[i][j] = (floatx4)0.0f;

    for (int k0 = 0; k0 < 1024; k0 += 32) {
        #pragma unroll
        for (int t = 0; t < 2; t++) {
            const int rbase = wave * 32 + t * 16;
            const int r = rbase + lrow;
            async16(A  + (size_t)(bm + r) * 1024 + k0 + lcol, &As[rbase * 32]);
            async16(Bt + (size_t)(bn + r) * 1024 + k0 + lcol, &Bs[rbase * 32]);
        }
        __syncthreads();
        short8 af[4], bfr[4];
        #pragma unroll
        for (int i = 0; i < 4; i++)
            af[i] = *(const short8*)&As[(wr * 64 + i * 16 + lr) * 32 + quad * 8];
        #pragma unroll
        for (int j = 0; j < 4; j++)
            bfr[j] = *(const short8*)&Bs[(wc * 64 + j * 16 + lr) * 32 + quad * 8];
        #pragma unroll
        for (int i = 0; i < 4; i++)
            #pragma unroll
            for (int j = 0; j < 4; j++)
                acc[i][j] = __builtin_amdgcn_mfma_f32_16x16x32_bf16(af[i], bfr[j], acc[i][j], 0, 0, 0);
        __syncthreads();
    }
    #pragma unroll
    for (int i = 0; i < 4; i++)
        #pragma unroll
        for (int j = 0; j < 4; j++)
            #pragma unroll
            for (int r = 0; r < 4; r++) {
                int row = bm + wr * 64 + i * 16 + quad * 4 + r;
                int col = bn + wc * 64 + j * 16 + lr;
                C[(size_t)row * 1024 + col] = acc[i][j][r];
            }
}

// ---------------------------------------------------------------------------
// attn_denom: block = (b, 64 l x 64 m). Loops 16 heads; Q/K tiles staged
// swizzled in LDS; next head's tiles prefetched into registers. Stores
// reciprocal denom in transposed-C-tile order drpT[b][mt][lt][256].
// ---------------------------------------------------------------------------
__global__ __launch_bounds__(256, 4) void attn_denom(
    const unsigned short* __restrict__ qb, const unsigned short* __restrict__ kb,
    unsigned short* __restrict__ drpT)
{
    __shared__ __align__(16) unsigned short Qs[64 * 64];
    __shared__ __align__(16) unsigned short Ks[64 * 64];
    const int tid = threadIdx.x, wave = tid >> 6, lane = tid & 63;
    const int quad = lane >> 4, lr = lane & 15;
    const int M0 = blockIdx.x * 64, L0 = blockIdx.y * 64, b = blockIdx.z;
    const int srow = tid >> 3, sblk = tid & 7;       // rows srow, srow+32
    const int sphys = (sblk ^ (srow & 7)) * 8;

    floatx4 e[4];
    #pragma unroll
    for (int i = 0; i < 4; i++) e[i] = (floatx4)0.0f;

    {
        const size_t hb = ((size_t)(b * 16)) << 17;
        short8 q0 = *(const short8*)(qb + hb + (size_t)(L0 + srow) * 64 + sblk * 8);
        short8 q1 = *(const short8*)(qb + hb + (size_t)(L0 + srow + 32) * 64 + sblk * 8);
        short8 k0 = *(const short8*)(kb + hb + (size_t)(M0 + srow) * 64 + sblk * 8);
        short8 k1 = *(const short8*)(kb + hb + (size_t)(M0 + srow + 32) * 64 + sblk * 8);
        *(short8*)&Qs[srow * 64 + sphys] = q0;
        *(short8*)&Qs[(srow + 32) * 64 + sphys] = q1;
        *(short8*)&Ks[srow * 64 + sphys] = k0;
        *(short8*)&Ks[(srow + 32) * 64 + sphys] = k1;
    }
    __syncthreads();

    for (int h = 0; h < 16; h++) {
        short8 qn0, qn1, kn0, kn1;
        if (h < 15) {
            const size_t hb = ((size_t)(b * 16 + h + 1)) << 17;
            qn0 = *(const short8*)(qb + hb + (size_t)(L0 + srow) * 64 + sblk * 8);
            qn1 = *(const short8*)(qb + hb + (size_t)(L0 + srow + 32) * 64 + sblk * 8);
            kn0 = *(const short8*)(kb + hb + (size_t)(M0 + srow) * 64 + sblk * 8);
            kn1 = *(const short8*)(kb + hb + (size_t)(M0 + srow + 32) * 64 + sblk * 8);
        }
        const int rq = wave * 16 + lr;
        short8 qf0 = *(const short8*)&Qs[rq * 64 + ((quad) ^ (lr & 7)) * 8];
        short8 qf1 = *(const short8*)&Qs[rq * 64 + ((4 + quad) ^ (lr & 7)) * 8];
        #pragma unroll
        for (int mt = 0; mt < 4; mt++) {
            const int rk = mt * 16 + lr;
            short8 kf0 = *(const short8*)&Ks[rk * 64 + ((quad) ^ (lr & 7)) * 8];
            short8 kf1 = *(const short8*)&Ks[rk * 64 + ((4 + quad) ^ (lr & 7)) * 8];
            floatx4 s = (floatx4)0.0f;
            s = __builtin_amdgcn_mfma_f32_16x16x32_bf16(kf0, qf0, s, 0, 0, 0);
            s = __builtin_amdgcn_mfma_f32_16x16x32_bf16(kf1, qf1, s, 0, 0, 0);
            e[mt][0] += __builtin_amdgcn_exp2f(s[0]);
            e[mt][1] += __builtin_amdgcn_exp2f(s[1]);
            e[mt][2] += __builtin_amdgcn_exp2f(s[2]);
            e[mt][3] += __builtin_amdgcn_exp2f(s[3]);
        }
        __syncthreads();
        if (h < 15) {
            *(short8*)&Qs[srow * 64 + sphys] = qn0;
            *(short8*)&Qs[(srow + 32) * 64 + sphys] = qn1;
            *(short8*)&Ks[srow * 64 + sphys] = kn0;
            *(short8*)&Ks[(srow + 32) * 64 + sphys] = kn1;
            __syncthreads();
        }
    }
    #pragma unroll
    for (int mt = 0; mt < 4; mt++) {
        float r0 = __builtin_amdgcn_rcpf(e[mt][0]);
        float r1 = __builtin_amdgcn_rcpf(e[mt][1]);
        float r2 = __builtin_amdgcn_rcpf(e[mt][2]);
        float r3 = __builtin_amdgcn_rcpf(e[mt][3]);
        uint2 o;
        o.x = pack2bf(r0, r1);
        o.y = pack2bf(r2, r3);
        int mtg = (M0 >> 4) + mt;
        int ltg = (L0 >> 4) + wave;
        *(uint2*)(drpT + ((((size_t)b * 128 + mtg) * 128 + ltg) << 8) + lane * 4) = o;
    }
}

// ---------------------------------------------------------------------------
// attn_pv v4: R0 geometry (128 l-rows, 4 waves, 1024 blocks) with ALL
// streaming K and V staged via global_load_lds (un-sinkable: no dest reg, a
// full step to land before the barrier's vmcnt(0) drain). R0's register
// prefetches were silently sunk by the compiler (VGPR_Count=64 vs ~150
// declared live) -> every V/drp load paid raw L3 latency in-line. V in LDS
// also dedups the 4 waves' identical V reads. drp reload cluster pinned
// before PV via sched_barrier(0) so PV covers its latency. LDS 48 KB ->
// 3 blocks/CU; launch_bounds(256,3) leaves VGPR cap unconstraining.
// XCD swizzle: each XCD gets (1 batch, 8 heads, all L) -> K+V = 4 MB = L2.
// ---------------------------------------------------------------------------
__global__ __launch_bounds__(256, 3) void attn_pv(
    const unsigned short* __restrict__ qb, const unsigned short* __restrict__ kb,
    const unsigned short* __restrict__ vbt, const unsigned short* __restrict__ drpT,
    unsigned short* __restrict__ cb)
{
    __shared__ __align__(16) unsigned short Ks[2][64 * 64];  // 16 KB
    __shared__ __align__(16) unsigned short Vs[2][64 * 64];  // 16 KB
    __shared__ __align__(16) unsigned short Ps[128 * 64];    // 16 KB
    const int tid = threadIdx.x, wave = tid >> 6, lane = tid & 63;
    const int quad = lane >> 4, lr = lane & 15;
    const int e7 = lr & 7;
    // bijective XCD swizzle over 1024 blocks: XCD x -> (b = x>>1, 8 heads, 16 Lt)
    const int flat = blockIdx.x;
    const int swz = (flat & 7) * 128 + (flat >> 3);
    const int Lt = swz & 15;
    const int h = (swz >> 4) & 15;
    const int b = swz >> 8;
    const int L0 = Lt * 128;
    const size_t head = (size_t)(b * 16 + h);
    const unsigned short* qbase = qb + (head << 17);
    const unsigned short* kbase = kb + (head << 17);
    const unsigned short* vtb   = vbt + (head << 17);        // [64][2048]
    // drp base for this wave's two l-tiles (ltg = (L0>>4) + wave*2 + j)
    const unsigned short* dbase = drpT + (((size_t)b * 128 * 128 + (L0 >> 4) + wave * 2) << 8) + lane * 4;

    // staging lanes: dest row (within 32-row half) = wave*8 + (lane>>3),
    // dest col-block = lane&7; global source col-block pre-XOR'd by row&7
    // (involution) so linear LDS dest + XOR-swizzled read agree (rule 21).
    const int klr = lane >> 3;
    const int ksw = (lane & 7) ^ klr;
    const unsigned short* ksrc0 = kbase + (size_t)(wave * 8 + klr) * 64 + ksw * 8;
    const unsigned short* vsrc0 = vtb + (size_t)(wave * 8 + klr) * 2048 + ksw * 8;

    // Q B-fragments (rows L0 + wave*32 + j*16 + lr), loaded once
    short8 qf[2][2];
    #pragma unroll
    for (int j = 0; j < 2; j++) {
        const unsigned short* qr = qbase + (size_t)(L0 + wave * 32 + j * 16 + lr) * 64;
        qf[j][0] = *(const short8*)(qr + quad * 8);
        qf[j][1] = *(const short8*)(qr + 32 + quad * 8);
    }

    floatx4 oacc[2][4];
    #pragma unroll
    for (int i = 0; i < 2; i++)
        #pragma unroll
        for (int j = 0; j < 4; j++) oacc[i][j] = (floatx4)0.0f;

    // prologue: stage K(0),V(0); load drp(0)
    async16(ksrc0,             &Ks[0][(wave * 8) * 64]);
    async16(ksrc0 + 32 * 64,   &Ks[0][(32 + wave * 8) * 64]);
    async16(vsrc0,             &Vs[0][(wave * 8) * 64]);
    async16(vsrc0 + 32 * 2048, &Vs[0][(32 + wave * 8) * 64]);
    uint2 du[4][2];
    #pragma unroll
    for (int mt = 0; mt < 4; mt++)
        #pragma unroll
        for (int j = 0; j < 2; j++)
            du[mt][j] = *(const uint2*)(dbase + ((size_t)mt << 15) + (j << 8));
    __syncthreads();

    for (int t = 0; t < 32; t++) {
        const int M0 = t * 64;
        const int cur = t & 1, nxt = cur ^ 1;
        // ---- issue async K(t+1), V(t+1) into the idle buffers ----
        if (t < 31) {
            const unsigned short* ks = ksrc0 + (size_t)(M0 + 64) * 64;
            const unsigned short* vs = vsrc0 + (M0 + 64);
            async16(ks,             &Ks[nxt][(wave * 8) * 64]);
            async16(ks + 32 * 64,   &Ks[nxt][(32 + wave * 8) * 64]);
            async16(vs,             &Vs[nxt][(wave * 8) * 64]);
            async16(vs + 32 * 2048, &Vs[nxt][(32 + wave * 8) * 64]);
        }
        // ---- S phase: 4 mt x 2 j S^T tiles; P -> wave-private LDS ----
        const unsigned short* ksp = &Ks[cur][0];
        #pragma unroll
        for (int mt = 0; mt < 4; mt++) {
            const int rk = mt * 16 + lr;
            short8 kf0 = *(const short8*)&ksp[rk * 64 + (quad ^ e7) * 8];
            short8 kf1 = *(const short8*)&ksp[rk * 64 + ((4 + quad) ^ e7) * 8];
            #pragma unroll
            for (int j = 0; j < 2; j++) {
                uint2 duv = du[mt][j];
                floatx4 s = (floatx4)0.0f;
                __builtin_amdgcn_s_setprio(1);
                s = __builtin_amdgcn_mfma_f32_16x16x32_bf16(kf0, qf[j][0], s, 0, 0, 0);
                s = __builtin_amdgcn_mfma_f32_16x16x32_bf16(kf1, qf[j][1], s, 0, 0, 0);
                __builtin_amdgcn_s_setprio(0);
                float r0 = __uint_as_float(duv.x << 16);
                float r1 = __uint_as_float(duv.x & 0xffff0000u);
                float r2 = __uint_as_float(duv.y << 16);
                float r3 = __uint_as_float(duv.y & 0xffff0000u);
                float p0 = __builtin_amdgcn_exp2f(s[0]) * r0;
                float p1 = __builtin_amdgcn_exp2f(s[1]) * r1;
                float p2 = __builtin_amdgcn_exp2f(s[2]) * r2;
                float p3 = __builtin_amdgcn_exp2f(s[3]) * r3;
                uint2 o;
                o.x = pack2bf(p0, p1);
                o.y = pack2bf(p2, p3);
                const int l_loc = wave * 32 + j * 16 + lr;
                const int lb16 = mt * 2 + (quad >> 1);
                *(uint2*)&Ps[l_loc * 64 + (lb16 ^ e7) * 8 + (quad & 1) * 4] = o;
            }
        }
        // ---- drp reload for t+1, pinned before PV so PV covers its latency ----
        if (t < 31) {
            #pragma unroll
            for (int mt = 0; mt < 4; mt++)
                #pragma unroll
                for (int j = 0; j < 2; j++)
                    du[mt][j] = *(const uint2*)(dbase + (((size_t)((t + 1) * 4 + mt)) << 15) + (j << 8));
        }
        __builtin_amdgcn_sched_barrier(0);
        // ---- PV phase: wave-private P A-frags + LDS V B-frags ----
        const unsigned short* vsp = &Vs[cur][0];
        #pragma unroll
        for (int f = 0; f < 2; f++) {
            short8 pf[2], vf[4];
            #pragma unroll
            for (int i2 = 0; i2 < 2; i2++)
                pf[i2] = *(const short8*)&Ps[(wave * 32 + i2 * 16 + lr) * 64 + ((f * 4 + quad) ^ e7) * 8];
            #pragma unroll
            for (int j2 = 0; j2 < 4; j2++) {
                const int rv = j2 * 16 + lr;
                vf[j2] = *(const short8*)&vsp[rv * 64 + ((f * 4 + quad) ^ e7) * 8];
            }
            __builtin_amdgcn_s_setprio(1);
            #pragma unroll
            for (int j2 = 0; j2 < 4; j2++)
                #pragma unroll
                for (int i2 = 0; i2 < 2; i2++)
                    oacc[i2][j2] = __builtin_amdgcn_mfma_f32_16x16x32_bf16(
                        pf[i2], vf[j2], oacc[i2][j2], 0, 0, 0);
            __builtin_amdgcn_s_setprio(0);
        }
        // ---- single barrier per step (drains async K/V(t+1); full step gap) ----
        if (t < 31) __syncthreads();
    }
    // epilogue: concat layout cb[b*2048 + l][h*64 + n]
    #pragma unroll
    for (int i2 = 0; i2 < 2; i2++)
        #pragma unroll
        for (int j2 = 0; j2 < 4; j2++)
            #pragma unroll
            for (int r = 0; r < 4; r++) {
                int row = L0 + wave * 32 + i2 * 16 + quad * 4 + r;
                int col = h * 64 + j2 * 16 + lr;
                cb[(size_t)(b * 2048 + row) * 1024 + col] = f2bf(oacc[i2][j2][r]);
            }
}

extern "C" void kernel_launch(void* const* d_in, const int* in_sizes, int n_in,
                              void* d_out, int out_size, void* d_ws, size_t ws_size,
                              hipStream_t stream) {
    const float* x    = (const float*)d_in[0];   // [4,2048,1024]
    const float* wqkv = (const float*)d_in[1];   // [1024,3072]
    const float* wo   = (const float*)d_in[2];   // [1024,1024]
    float* out = (float*)d_out;                  // [4,2048,1024] fp32

    // workspace: 100,663,296 bytes with overlays
    unsigned short* W = (unsigned short*)d_ws;
    unsigned short* qb   = W;                    // [4,16,2048,64] pre-scaled Q
    unsigned short* kb   = W + 8388608;          // [4,16,2048,64]
    unsigned short* vbt  = W + 16777216;         // [4,16,64,2048] V^T
    unsigned short* drpT = W + 25165824;         // [4][128mt][128lt][256] recip denom
    unsigned short* cb   = W + 41943040;         // [8192,1024] concat
    // overlays (lifetime-disjoint):
    unsigned short* xb    = drpT;                // bf16 x   (dead before denom)
    unsigned short* wqkvT = drpT + 8388608;      // bf16 wqkv^T [3072][1024]
    unsigned short* vb    = cb;                  // V row-major (dead before pv)
    unsigned short* woT   = drpT;                // bf16 wo^T [1024][1024] (after pv)

    cvt_bf16  <<<4096, 256, 0, stream>>>(x, xb, 1048576);
    tcvt      <<<dim3(48, 16), 256, 0, stream>>>(wqkv, wqkvT, 1024, 3072);
    qkv_gemm  <<<dim3(24, 64), 256, 0, stream>>>(xb, wqkvT, qb, kb, vb);
    vtrans    <<<dim3(32, 64), 256, 0, stream>>>(vb, vbt);
    attn_denom<<<dim3(32, 32, 4), 256, 0, stream>>>(qb, kb, drpT);
    attn_pv   <<<1024, 256, 0, stream>>>(qb, kb, vbt, drpT, cb);
    tcvt      <<<dim3(16, 16), 256, 0, stream>>>(wo, woT, 1024, 1024);
    out_gemm  <<<dim3(8, 64), 256, 0, stream>>>(cb, woT, out);
}